// Round 12
// baseline (75.211 us; speedup 1.0000x reference)
//
#include <hip/hip_runtime.h>
#include <hip/hip_bf16.h>
#include <stdint.h>

typedef short bf16x8 __attribute__((ext_vector_type(8)));
typedef unsigned short u16x8 __attribute__((ext_vector_type(8)));
typedef float f32x4 __attribute__((ext_vector_type(4)));

__device__ inline unsigned short f2bf(float f) {
    union { float f; uint32_t u; } v; v.f = f;
    uint32_t lsb = (v.u >> 16) & 1u;
    v.u += 0x7fffu + lsb;                // round-to-nearest-even
    return (unsigned short)(v.u >> 16);
}

// pack 2 f32 -> 2 bf16 in one u32 (no builtin on gfx950), RNE
__device__ inline uint32_t cvt_pk_bf16(float lo, float hi) {
    uint32_t r;
    asm("v_cvt_pk_bf16_f32 %0, %1, %2" : "=v"(r) : "v"(lo), "v"(hi));
    return r;
}

// async 16B global -> LDS (dest = wave-uniform base + lane*16)
__device__ inline void gload16(const unsigned short* g, unsigned short* l) {
    __builtin_amdgcn_global_load_lds(
        (const __attribute__((address_space(1))) unsigned int*)g,
        (__attribute__((address_space(3))) unsigned int*)l, 16, 0, 0);
}

// ---------------- merged prep: cast x -> bf16, transpose+cast both weights
__global__ __launch_bounds__(256) void prep(const float* __restrict__ x,
                                            const float* __restrict__ wa,
                                            const float* __restrict__ wp,
                                            unsigned short* __restrict__ xbf,
                                            unsigned short* __restrict__ waT,
                                            unsigned short* __restrict__ wpT) {
    __shared__ float tile[64][65];
    const int t = threadIdx.x;
    const int id = blockIdx.x;
    if (id < 1536) {
        const int i = id * 256 + t;
        const float4* p = (const float4*)x + (size_t)i * 2;
        float4 a = p[0], b = p[1];
        u16x8 o;
        o[0] = f2bf(a.x); o[1] = f2bf(a.y); o[2] = f2bf(a.z); o[3] = f2bf(a.w);
        o[4] = f2bf(b.x); o[5] = f2bf(b.y); o[6] = f2bf(b.z); o[7] = f2bf(b.w);
        *((u16x8*)xbf + i) = o;
        return;
    }
    const float* in; unsigned short* out; int R, C, bx, by;
    if (id < 1968) { int k = id - 1536; in = wa; out = waT; R = 768; C = 2304; bx = k % 36; by = k / 36; }
    else           { int k = id - 1968; in = wp; out = wpT; R = 768; C = 768;  bx = k % 12; by = k / 12; }
    const int r0 = by * 64, c0 = bx * 64;
    {
        int r = t >> 2, cs = t & 3;
        #pragma unroll
        for (int i = 0; i < 4; ++i) {
            int c = (cs * 4 + i) * 4;
            float4 v = *(const float4*)(in + (size_t)(r0 + r) * C + c0 + c);
            tile[r][c] = v.x; tile[r][c + 1] = v.y; tile[r][c + 2] = v.z; tile[r][c + 3] = v.w;
        }
    }
    __syncthreads();
    {
        int c = t >> 2, rs = t & 3;
        #pragma unroll
        for (int i = 0; i < 2; ++i) {
            u16x8 o;
            #pragma unroll
            for (int e = 0; e < 8; ++e) o[e] = f2bf(tile[rs * 16 + i * 8 + e][c]);
            *(u16x8*)(out + (size_t)(c0 + c) * R + r0 + rs * 16 + i * 8) = o;
        }
    }
}

// ---------------- GEMM1: 64x128 tile, BK=32 (24 KiB LDS -> 4+ blocks/CU),
// 4 waves as 2Mx2N (each 32x64 = 2x4 frags), 2-phase dbuf global_load_lds,
// XOR swizzle for BK=32 rows (seg' = seg ^ (row&3)).
// WRITE_VT: qkv V third (col >= 1536) written transposed into vT.
template <int OUT_BF16, int WRITE_VT>
__global__ __launch_bounds__(256) void gemm_bk32(const unsigned short* __restrict__ A,
                                                 const unsigned short* __restrict__ BT,
                                                 const float* __restrict__ bias,
                                                 void* __restrict__ Cout,
                                                 unsigned short* __restrict__ vTout,
                                                 int M, int N, int K) {
    __shared__ unsigned short As[2][64 * 32];
    __shared__ unsigned short Bs[2][128 * 32];
    const int tid = threadIdx.x;
    const int lane = tid & 63;
    const int w = tid >> 6;
    const int wr = w >> 1, wc = w & 1;
    const int row0 = blockIdx.y * 64, col0 = blockIdx.x * 128;

    const int srow = lane >> 2;                  // 0..15 row within 16-row chunk
    const int sseg = (lane & 3) ^ (srow & 3);    // swizzled source 16B segment (of 4)

    const int nt = K >> 5;

    f32x4 acc[2][4] = {};

#define STAGE(buf, k0)                                                                     \
    {                                                                                      \
        gload16(A + (size_t)(row0 + w * 16 + srow) * K + (k0) + sseg * 8,                  \
                &As[buf][w * 512]);                                                        \
        _Pragma("unroll")                                                                  \
        for (int i = 0; i < 2; ++i) {                                                      \
            const int ch = w * 2 + i;                                                      \
            gload16(BT + (size_t)(col0 + ch * 16 + srow) * K + (k0) + sseg * 8,            \
                    &Bs[buf][ch * 512]);                                                   \
        }                                                                                  \
    }

    STAGE(0, 0);
    int cur = 0;
    for (int t = 0; t < nt; ++t) {
        __syncthreads();   // drains vmcnt -> buf[cur] ready; prev-iter reads of buf[cur^1] done
        if (t + 1 < nt) {
            if (cur) STAGE(0, (t + 1) << 5) else STAGE(1, (t + 1) << 5);
        }
        const unsigned short* as = As[cur];
        const unsigned short* bs = Bs[cur];
        // read seg: want global seg (lane>>4); stored at seg' = (lane>>4) ^ (row&3),
        // row&3 == lane&3 for all fragment rows (row = base16*k + (lane&15))
        const int cs = ((lane >> 4) ^ (lane & 3)) << 3;
        bf16x8 af[2], bfr[4];
        #pragma unroll
        for (int m = 0; m < 2; ++m)
            af[m] = *(const bf16x8*)(as + (wr * 32 + m * 16 + (lane & 15)) * 32 + cs);
        #pragma unroll
        for (int n = 0; n < 4; ++n)
            bfr[n] = *(const bf16x8*)(bs + (wc * 64 + n * 16 + (lane & 15)) * 32 + cs);
        #pragma unroll
        for (int m = 0; m < 2; ++m)
            #pragma unroll
            for (int n = 0; n < 4; ++n)
                acc[m][n] = __builtin_amdgcn_mfma_f32_16x16x32_bf16(af[m], bfr[n], acc[m][n], 0, 0, 0);
        cur ^= 1;
    }
#undef STAGE

    if (WRITE_VT && col0 >= 1536) {
        #pragma unroll
        for (int m = 0; m < 2; ++m) {
            int row = row0 + wr * 32 + m * 16 + (lane >> 4) * 4;
            #pragma unroll
            for (int n = 0; n < 4; ++n) {
                int col = col0 + wc * 64 + n * 16 + (lane & 15);
                float bb = bias[col];
                uint2 st;
                st.x = cvt_pk_bf16(acc[m][n][0] + bb, acc[m][n][1] + bb);
                st.y = cvt_pk_bf16(acc[m][n][2] + bb, acc[m][n][3] + bb);
                *(uint2*)(vTout + (size_t)(col - 1536) * 4096 + row) = st;
            }
        }
        return;
    }

    #pragma unroll
    for (int m = 0; m < 2; ++m) {
        int row = row0 + wr * 32 + m * 16 + (lane >> 4) * 4;
        #pragma unroll
        for (int n = 0; n < 4; ++n) {
            int col = col0 + wc * 64 + n * 16 + (lane & 15);
            float bb = bias[col];
            #pragma unroll
            for (int r = 0; r < 4; ++r) {
                float v = acc[m][n][r] + bb;
                if (OUT_BF16)
                    ((unsigned short*)Cout)[(size_t)(row + r) * N + col] = f2bf(v);
                else
                    ((float*)Cout)[(size_t)(row + r) * N + col] = v;
            }
        }
    }
}

// ---------------- GEMM2: 64x64 tile, BK=64 (768 blocks -> 3/CU), 4 waves as
// 2Mx2N (each 32x32 = 2x2 frags). Same proven 2-phase + BK=64 XOR swizzle.
__global__ __launch_bounds__(256) void gemm2_64(const unsigned short* __restrict__ A,
                                                const unsigned short* __restrict__ BT,
                                                const float* __restrict__ bias,
                                                float* __restrict__ Cout,
                                                int M, int N, int K) {
    __shared__ unsigned short As[2][64 * 64];
    __shared__ unsigned short Bs[2][64 * 64];
    const int tid = threadIdx.x;
    const int lane = tid & 63;
    const int w = tid >> 6;
    const int wr = w >> 1, wc = w & 1;
    const int row0 = blockIdx.y * 64, col0 = blockIdx.x * 64;

    const int srow = lane >> 3;              // 0..7 row within 8-row chunk
    const int sseg = (lane & 7) ^ srow;      // swizzled source 16B segment

    const int nt = K >> 6;

    f32x4 acc[2][2] = {};

#define STAGE(buf, k0)                                                                     \
    {                                                                                      \
        _Pragma("unroll")                                                                  \
        for (int i = 0; i < 2; ++i) {                                                      \
            const int ch = w * 2 + i;                                                      \
            const int r = ch * 8 + srow;                                                   \
            gload16(A + (size_t)(row0 + r) * K + (k0) + sseg * 8, &As[buf][ch * 512]);     \
            gload16(BT + (size_t)(col0 + r) * K + (k0) + sseg * 8, &Bs[buf][ch * 512]);    \
        }                                                                                  \
    }

    STAGE(0, 0);
    int cur = 0;
    for (int t = 0; t < nt; ++t) {
        __syncthreads();
        if (t + 1 < nt) {
            if (cur) STAGE(0, (t + 1) << 6) else STAGE(1, (t + 1) << 6);
        }
        const unsigned short* as = As[cur];
        const unsigned short* bs = Bs[cur];
        const int c0s = ((0 + (lane >> 4)) ^ (lane & 7)) << 3;
        const int c1s = ((4 + (lane >> 4)) ^ (lane & 7)) << 3;
        bf16x8 af[2][2], bfr[2][2];
        #pragma unroll
        for (int m = 0; m < 2; ++m) {
            const int ra = (wr * 32 + m * 16 + (lane & 15)) * 64;
            af[0][m] = *(const bf16x8*)(as + ra + c0s);
            af[1][m] = *(const bf16x8*)(as + ra + c1s);
        }
        #pragma unroll
        for (int n = 0; n < 2; ++n) {
            const int rb = (wc * 32 + n * 16 + (lane & 15)) * 64;
            bfr[0][n] = *(const bf16x8*)(bs + rb + c0s);
            bfr[1][n] = *(const bf16x8*)(bs + rb + c1s);
        }
        #pragma unroll
        for (int ks = 0; ks < 2; ++ks)
            #pragma unroll
            for (int m = 0; m < 2; ++m)
                #pragma unroll
                for (int n = 0; n < 2; ++n)
                    acc[m][n] = __builtin_amdgcn_mfma_f32_16x16x32_bf16(af[ks][m], bfr[ks][n], acc[m][n], 0, 0, 0);
        cur ^= 1;
    }
#undef STAGE

    #pragma unroll
    for (int m = 0; m < 2; ++m) {
        int row = row0 + wr * 32 + m * 16 + (lane >> 4) * 4;
        #pragma unroll
        for (int n = 0; n < 2; ++n) {
            int col = col0 + wc * 32 + n * 16 + (lane & 15);
            float bb = bias[col];
            #pragma unroll
            for (int r = 0; r < 4; ++r)
                Cout[(size_t)(row + r) * N + col] = acc[m][n][r] + bb;
        }
    }
}

// ---------------- flash-style sink+window attention, swapped-operand MFMA.
// (r8 version verbatim — best measured config: 64-row Q blocks, 4 waves)
__global__ __launch_bounds__(256) void attn_mfma(const unsigned short* __restrict__ qkv,
                                                 const unsigned short* __restrict__ vT,
                                                 unsigned short* __restrict__ ctx,
                                                 const int* __restrict__ pnsink,
                                                 const int* __restrict__ pwin) {
    __shared__ unsigned short Ks0[80 * 64];              // rows 64..79: sink K (keys 0..15)
    __shared__ unsigned short Vs0[64 * 64 + 2 * 64 * 8]; // main + V^T sink cols 0..7 / 8..15
    __shared__ unsigned short Ks1[64 * 64];
    __shared__ unsigned short Vs1[64 * 64];
    const int tid = threadIdx.x, lane = tid & 63, w = tid >> 6;
    const int q = lane & 15, g = lane >> 4;
    const int h = blockIdx.y;
    const int bx = ((blockIdx.x & 7) << 3) | (blockIdx.x >> 3);   // XCD-chunked, bijective
    const int i0 = bx << 6;
    const int nsink = *pnsink, wsize = *pwin;
    const int D3 = 2304;
    const int iq = i0 + 16 * w + q;
    const float SC = 0.18033688011112042f;   // 0.125 * log2(e): softmax in exp2 domain

    const int sseg = (lane & 7) ^ (lane >> 3);

    const unsigned short* qrow = qkv + (size_t)iq * D3 + h * 64 + g * 8;
    const bf16x8 aq0 = *(const bf16x8*)(qrow);
    const bf16x8 aq1 = *(const bf16x8*)(qrow + 32);

    float m_run = -1e30f, l_run = 0.f;
    f32x4 octx[4] = {};

    int wlo = i0 - wsize + 1; if (wlo < 0) wlo = 0;
    const int t_lo = (wlo >> 6) << 6;
    const bool ext = (t_lo > 0);             // sinks detached -> fold into tile 0
    const int ntiles = ((i0 - t_lo) >> 6) + 1;

    const int sl01 = q + ((g & 1) << 5);
    const int sl23 = sl01 + 16;
    const int x7 = q & 7;
    const int ck0 = ((0 + g) ^ x7) << 3;
    const int ck1 = ((4 + g) ^ x7) << 3;

#define ASTAGE(KSB, VSB, kb)                                                           \
    {                                                                                  \
        _Pragma("unroll")                                                              \
        for (int i = 0; i < 2; ++i) {                                                  \
            const int ch = w * 2 + i;                                                  \
            const int r = ch * 8 + (lane >> 3);                                        \
            gload16(qkv + (size_t)((kb) + r) * D3 + 768 + h * 64 + sseg * 8,           \
                    (KSB) + ch * 512);                                                 \
            gload16(vT + ((size_t)h * 64 + r) * 4096 + (kb) + sseg * 8,                \
                    (VSB) + ch * 512);                                                 \
        }                                                                              \
    }

    ASTAGE(Ks0, Vs0, t_lo);
    if (ext) {   // one extra gload16 per wave: K rows 0..15 and V^T cols 0..15
        if (w == 0)      gload16(qkv + (size_t)(lane >> 3) * D3 + 768 + h * 64 + sseg * 8, Ks0 + 4096);
        else if (w == 1) gload16(qkv + (size_t)(8 + (lane >> 3)) * D3 + 768 + h * 64 + sseg * 8, Ks0 + 4096 + 512);
        else if (w == 2) gload16(vT + ((size_t)h * 64 + lane) * 4096, Vs0 + 4096);
        else             gload16(vT + ((size_t)h * 64 + lane) * 4096 + 8, Vs0 + 4096 + 1024);
    }

    for (int tt = 0; tt < ntiles; ++tt) {
        __syncthreads();   // buf[tt&1] ready; prev reads of other buf done
        if (tt + 1 < ntiles) {
            const int kbn = t_lo + ((tt + 1) << 6);
            if (tt & 1) ASTAGE(Ks0, Vs0, kbn) else ASTAGE(Ks1, Vs1, kbn);
        }
        const int kb = t_lo + (tt << 6);
        const unsigned short* ks_ = (tt & 1) ? Ks1 : Ks0;
        const unsigned short* vs_ = (tt & 1) ? Vs1 : Vs0;
        const bool extt = ext && (tt == 0);
        const int NB = extt ? 5 : 4;   // wave-uniform

        f32x4 sacc[5] = {};
        __builtin_amdgcn_s_setprio(1);
        #pragma unroll
        for (int nb = 0; nb < 5; ++nb) {
            if (nb < NB) {
                const int rr = (nb * 16 + q) * 64;
                bf16x8 k0 = *(const bf16x8*)(ks_ + rr + ck0);
                bf16x8 k1 = *(const bf16x8*)(ks_ + rr + ck1);
                sacc[nb] = __builtin_amdgcn_mfma_f32_16x16x32_bf16(k0, aq0, sacc[nb], 0, 0, 0);
                sacc[nb] = __builtin_amdgcn_mfma_f32_16x16x32_bf16(k1, aq1, sacc[nb], 0, 0, 0);
            }
        }
        __builtin_amdgcn_s_setprio(0);

        float vmax = -1e30f;
        #pragma unroll
        for (int nb = 0; nb < 5; ++nb)
            if (nb < NB)
                #pragma unroll
                for (int r = 0; r < 4; ++r) {
                    const int slot = nb * 16 + g * 4 + r;
                    const int j = (slot >= 64) ? (slot - 64) : kb + slot;
                    const bool vis = (j <= iq) && ((j < nsink) || (j > iq - wsize));
                    sacc[nb][r] = vis ? sacc[nb][r] * SC : -1e30f;
                    vmax = fmaxf(vmax, sacc[nb][r]);
                }
        vmax = fmaxf(vmax, __shfl_xor(vmax, 16));
        vmax = fmaxf(vmax, __shfl_xor(vmax, 32));

        const bool upd = !__all(vmax <= m_run + 8.f);
        if (upd) {
            const float mn = fmaxf(m_run, vmax);
            const float alpha = __builtin_amdgcn_exp2f(m_run - mn);
            l_run *= alpha;
            #pragma unroll
            for (int nb = 0; nb < 4; ++nb)
                #pragma unroll
                for (int r = 0; r < 4; ++r) octx[nb][r] *= alpha;
            m_run = mn;
        }
        float p[5][4];
        float lsum = 0.f;
        #pragma unroll
        for (int nb = 0; nb < 5; ++nb)
            if (nb < NB)
                #pragma unroll
                for (int r = 0; r < 4; ++r) {
                    const float pv = __builtin_amdgcn_exp2f(sacc[nb][r] - m_run);
                    p[nb][r] = pv;
                    lsum += pv;
                }
        lsum += __shfl_xor(lsum, 16);
        lsum += __shfl_xor(lsum, 32);
        l_run += lsum;

        uint32_t c01[5][2];
        #pragma unroll
        for (int nb = 0; nb < 5; ++nb)
            if (nb < NB) {
                c01[nb][0] = cvt_pk_bf16(p[nb][0], p[nb][1]);
                c01[nb][1] = cvt_pk_bf16(p[nb][2], p[nb][3]);
            }

        __builtin_amdgcn_s_setprio(1);
        #pragma unroll
        for (int ks = 0; ks < 2; ++ks) {
            uint32_t f00 = (uint32_t)__shfl((int)c01[2 * ks + 0][0], sl01);
            uint32_t f01 = (uint32_t)__shfl((int)c01[2 * ks + 1][0], sl01);
            uint32_t f10 = (uint32_t)__shfl((int)c01[2 * ks + 0][1], sl01);
            uint32_t f11 = (uint32_t)__shfl((int)c01[2 * ks + 1][1], sl01);
            uint32_t f20 = (uint32_t)__shfl((int)c01[2 * ks + 0][0], sl23);
            uint32_t f21 = (uint32_t)__shfl((int)c01[2 * ks + 1][0], sl23);
            uint32_t f30 = (uint32_t)__shfl((int)c01[2 * ks + 0][1], sl23);
            uint32_t f31 = (uint32_t)__shfl((int)c01[2 * ks + 1][1], sl23);
            union { uint32_t u[4]; bf16x8 v; } pa;
            pa.u[0] = (g >> 1) ? f01 : f00;
            pa.u[1] = (g >> 1) ? f11 : f10;
            pa.u[2] = (g >> 1) ? f21 : f20;
            pa.u[3] = (g >> 1) ? f31 : f30;
            const int cv = ((ks * 4 + g) ^ x7) << 3;
            #pragma unroll
            for (int nb = 0; nb < 4; ++nb) {
                bf16x8 bv = *(const bf16x8*)(vs_ + (nb * 16 + q) * 64 + cv);
                octx[nb] = __builtin_amdgcn_mfma_f32_16x16x32_bf16(bv, pa.v, octx[nb], 0, 0, 0);
            }
        }
        if (extt) {
            uint32_t e0 = (uint32_t)__shfl((int)c01[4][0], sl01);
            uint32_t e1 = (uint32_t)__shfl((int)c01[4][1], sl01);
            uint32_t e2 = (uint32_t)__shfl((int)c01[4][0], sl23);
            uint32_t e3 = (uint32_t)__shfl((int)c01[4][1], sl23);
            union { uint32_t u[4]; bf16x8 v; } pa;
            const bool lo = (g < 2);
            pa.u[0] = lo ? e0 : 0u;
            pa.u[1] = lo ? e1 : 0u;
            pa.u[2] = lo ? e2 : 0u;
            pa.u[3] = lo ? e3 : 0u;
            const unsigned short* vb = vs_ + 4096 + ((g & 1) << 10);
            #pragma unroll
            for (int nb = 0; nb < 4; ++nb) {
                bf16x8 bv = *(const bf16x8*)(vb + (nb * 16 + q) * 8);
                octx[nb] = __builtin_amdgcn_mfma_f32_16x16x32_bf16(bv, pa.v, octx[nb], 0, 0, 0);
            }
        }
        __builtin_amdgcn_s_setprio(0);
    }
#undef ASTAGE

    const float inv = (l_run > 0.f) ? 1.f / l_run : 0.f;
    unsigned short* crow = ctx + (size_t)iq * 768 + h * 64 + g * 4;
    #pragma unroll
    for (int nb = 0; nb < 4; ++nb) {
        uint2 st;
        st.x = cvt_pk_bf16(octx[nb][0] * inv, octx[nb][1] * inv);
        st.y = cvt_pk_bf16(octx[nb][2] * inv, octx[nb][3] * inv);
        *(uint2*)(crow + nb * 16) = st;
    }
}

extern "C" void kernel_launch(void* const* d_in, const int* in_sizes, int n_in,
                              void* d_out, int out_size, void* d_ws, size_t ws_size,
                              hipStream_t stream) {
    const float* x      = (const float*)d_in[0];
    const float* w_attn = (const float*)d_in[1];
    const float* b_attn = (const float*)d_in[2];
    const float* w_proj = (const float*)d_in[3];
    const float* b_proj = (const float*)d_in[4];
    const int*   pnsink = (const int*)d_in[5];
    const int*   pwin   = (const int*)d_in[6];
    float* out = (float*)d_out;

    const int D = 768, S = 4096, N1 = 3 * D;

    unsigned short* xbf   = (unsigned short*)d_ws;
    unsigned short* waT   = xbf + (size_t)S * D;
    unsigned short* wpT   = waT + (size_t)N1 * D;
    unsigned short* qkvbf = wpT + (size_t)D * D;
    unsigned short* ctxbf = qkvbf + (size_t)S * N1;
    unsigned short* vTbf  = ctxbf + (size_t)S * D;

    // merged prep: cast x + transpose both weights (one launch)
    prep<<<2112, 256, 0, stream>>>(x, w_attn, w_proj, xbf, waT, wpT);

    // GEMM1 (64x128 tiles, BK=32, 1152 blocks ~4.5/CU): qkv; V third -> vT
    {
        dim3 g(N1 / 128, S / 64);
        gemm_bk32<1, 1><<<g, 256, 0, stream>>>(xbf, waT, b_attn, qkvbf, vTbf, S, N1, D);
    }
    // attention -> ctx bf16 [S, D]  (r8 proven config)
    {
        dim3 g(S / 64, 12);
        attn_mfma<<<g, 256, 0, stream>>>(qkvbf, vTbf, ctxbf, pnsink, pwin);
    }
    // GEMM2 (64x64 tiles, 768 blocks ~3/CU): out = ctx @ w_proj + b_proj -> f32
    {
        dim3 g(D / 64, S / 64);
        gemm2_64<<<g, 256, 0, stream>>>(ctxbf, wpT, b_proj, out, S, D, D);
    }
}

// Round 13
// 66.620 us; speedup vs baseline: 1.1290x; 1.1290x over previous
//
#include <hip/hip_runtime.h>
#include <hip/hip_bf16.h>
#include <stdint.h>

typedef short bf16x8 __attribute__((ext_vector_type(8)));
typedef unsigned short u16x8 __attribute__((ext_vector_type(8)));
typedef float f32x4 __attribute__((ext_vector_type(4)));

__device__ inline unsigned short f2bf(float f) {
    union { float f; uint32_t u; } v; v.f = f;
    uint32_t lsb = (v.u >> 16) & 1u;
    v.u += 0x7fffu + lsb;                // round-to-nearest-even
    return (unsigned short)(v.u >> 16);
}

// pack 2 f32 -> 2 bf16 in one u32 (no builtin on gfx950), RNE
__device__ inline uint32_t cvt_pk_bf16(float lo, float hi) {
    uint32_t r;
    asm("v_cvt_pk_bf16_f32 %0, %1, %2" : "=v"(r) : "v"(lo), "v"(hi));
    return r;
}

// async 16B global -> LDS (dest = wave-uniform base + lane*16)
__device__ inline void gload16(const unsigned short* g, unsigned short* l) {
    __builtin_amdgcn_global_load_lds(
        (const __attribute__((address_space(1))) unsigned int*)g,
        (__attribute__((address_space(3))) unsigned int*)l, 16, 0, 0);
}

// ---------------- merged prep: cast x -> bf16, transpose+cast both weights
__global__ __launch_bounds__(256) void prep(const float* __restrict__ x,
                                            const float* __restrict__ wa,
                                            const float* __restrict__ wp,
                                            unsigned short* __restrict__ xbf,
                                            unsigned short* __restrict__ waT,
                                            unsigned short* __restrict__ wpT) {
    __shared__ float tile[64][65];
    const int t = threadIdx.x;
    const int id = blockIdx.x;
    if (id < 1536) {
        const int i = id * 256 + t;
        const float4* p = (const float4*)x + (size_t)i * 2;
        float4 a = p[0], b = p[1];
        u16x8 o;
        o[0] = f2bf(a.x); o[1] = f2bf(a.y); o[2] = f2bf(a.z); o[3] = f2bf(a.w);
        o[4] = f2bf(b.x); o[5] = f2bf(b.y); o[6] = f2bf(b.z); o[7] = f2bf(b.w);
        *((u16x8*)xbf + i) = o;
        return;
    }
    const float* in; unsigned short* out; int R, C, bx, by;
    if (id < 1968) { int k = id - 1536; in = wa; out = waT; R = 768; C = 2304; bx = k % 36; by = k / 36; }
    else           { int k = id - 1968; in = wp; out = wpT; R = 768; C = 768;  bx = k % 12; by = k / 12; }
    const int r0 = by * 64, c0 = bx * 64;
    {
        int r = t >> 2, cs = t & 3;
        #pragma unroll
        for (int i = 0; i < 4; ++i) {
            int c = (cs * 4 + i) * 4;
            float4 v = *(const float4*)(in + (size_t)(r0 + r) * C + c0 + c);
            tile[r][c] = v.x; tile[r][c + 1] = v.y; tile[r][c + 2] = v.z; tile[r][c + 3] = v.w;
        }
    }
    __syncthreads();
    {
        int c = t >> 2, rs = t & 3;
        #pragma unroll
        for (int i = 0; i < 2; ++i) {
            u16x8 o;
            #pragma unroll
            for (int e = 0; e < 8; ++e) o[e] = f2bf(tile[rs * 16 + i * 8 + e][c]);
            *(u16x8*)(out + (size_t)(c0 + c) * R + r0 + rs * 16 + i * 8) = o;
        }
    }
}

// ---------------- bf16 MFMA GEMM: C = A[M,K] @ BT[N,K]^T + bias
// 64x128 tile (GEMM1 1152 blocks ~3/CU LDS-limited, GEMM2 384 blocks),
// BK=64, 4 waves as 2Mx2N (each 32x64 = 2x4 frags), 2-phase dbuf
// global_load_lds staging, XOR swizzle both-sides (row&7 == lane&7 preserved).
// WRITE_VT: qkv V third (col >= 1536) written transposed into vT.
template <int OUT_BF16, int WRITE_VT>
__global__ __launch_bounds__(256) void gemm_bf16(const unsigned short* __restrict__ A,
                                                 const unsigned short* __restrict__ BT,
                                                 const float* __restrict__ bias,
                                                 void* __restrict__ Cout,
                                                 unsigned short* __restrict__ vTout,
                                                 int M, int N, int K) {
    __shared__ unsigned short As[2][64 * 64];
    __shared__ unsigned short Bs[2][128 * 64];
    const int tid = threadIdx.x;
    const int lane = tid & 63;
    const int w = tid >> 6;
    const int wr = w >> 1, wc = w & 1;
    const int row0 = blockIdx.y * 64, col0 = blockIdx.x * 128;

    const int srow = lane >> 3;              // 0..7 row within 8-row chunk
    const int sseg = (lane & 7) ^ srow;      // swizzled source 16B segment

    const int nt = K >> 6;

    f32x4 acc[2][4] = {};

#define STAGE(buf, k0)                                                                     \
    {                                                                                      \
        _Pragma("unroll")                                                                  \
        for (int i = 0; i < 2; ++i) {                                                      \
            const int ch = w * 2 + i;                                                      \
            const int r = ch * 8 + srow;                                                   \
            gload16(A + (size_t)(row0 + r) * K + (k0) + sseg * 8, &As[buf][ch * 512]);     \
        }                                                                                  \
        _Pragma("unroll")                                                                  \
        for (int i = 0; i < 4; ++i) {                                                      \
            const int ch = w * 4 + i;                                                      \
            const int r = ch * 8 + srow;                                                   \
            gload16(BT + (size_t)(col0 + r) * K + (k0) + sseg * 8, &Bs[buf][ch * 512]);    \
        }                                                                                  \
    }

    STAGE(0, 0);
    int cur = 0;
    for (int t = 0; t < nt; ++t) {
        __syncthreads();   // drains vmcnt -> buf[cur] ready; prev-iter reads of buf[cur^1] done
        if (t + 1 < nt) {
            if (cur) STAGE(0, (t + 1) << 6) else STAGE(1, (t + 1) << 6);
        }
        const unsigned short* as = As[cur];
        const unsigned short* bs = Bs[cur];
        // swizzled read column (16B units): (ks*4 + lane>>4) ^ (row & 7); row&7 == lane&7
        const int c0s = ((0 + (lane >> 4)) ^ (lane & 7)) << 3;
        const int c1s = ((4 + (lane >> 4)) ^ (lane & 7)) << 3;
        bf16x8 af[2][2], bfr[2][4];
        #pragma unroll
        for (int m = 0; m < 2; ++m) {
            const int ra = (wr * 32 + m * 16 + (lane & 15)) * 64;
            af[0][m] = *(const bf16x8*)(as + ra + c0s);
            af[1][m] = *(const bf16x8*)(as + ra + c1s);
        }
        #pragma unroll
        for (int n = 0; n < 4; ++n) {
            const int rb = (wc * 64 + n * 16 + (lane & 15)) * 64;
            bfr[0][n] = *(const bf16x8*)(bs + rb + c0s);
            bfr[1][n] = *(const bf16x8*)(bs + rb + c1s);
        }
        #pragma unroll
        for (int ks = 0; ks < 2; ++ks)
            #pragma unroll
            for (int m = 0; m < 2; ++m)
                #pragma unroll
                for (int n = 0; n < 4; ++n)
                    acc[m][n] = __builtin_amdgcn_mfma_f32_16x16x32_bf16(af[ks][m], bfr[ks][n], acc[m][n], 0, 0, 0);
        cur ^= 1;
    }
#undef STAGE

    if (WRITE_VT && col0 >= 1536) {
        #pragma unroll
        for (int m = 0; m < 2; ++m) {
            int row = row0 + wr * 32 + m * 16 + (lane >> 4) * 4;
            #pragma unroll
            for (int n = 0; n < 4; ++n) {
                int col = col0 + wc * 64 + n * 16 + (lane & 15);
                float bb = bias[col];
                uint2 st;
                st.x = cvt_pk_bf16(acc[m][n][0] + bb, acc[m][n][1] + bb);
                st.y = cvt_pk_bf16(acc[m][n][2] + bb, acc[m][n][3] + bb);
                *(uint2*)(vTout + (size_t)(col - 1536) * 4096 + row) = st;
            }
        }
        return;
    }

    #pragma unroll
    for (int m = 0; m < 2; ++m) {
        int row = row0 + wr * 32 + m * 16 + (lane >> 4) * 4;
        #pragma unroll
        for (int n = 0; n < 4; ++n) {
            int col = col0 + wc * 64 + n * 16 + (lane & 15);
            float bb = bias[col];
            #pragma unroll
            for (int r = 0; r < 4; ++r) {
                float v = acc[m][n][r] + bb;
                if (OUT_BF16)
                    ((unsigned short*)Cout)[(size_t)(row + r) * N + col] = f2bf(v);
                else
                    ((float*)Cout)[(size_t)(row + r) * N + col] = v;
            }
        }
    }
}

// ---------------- flash-style sink+window attention, swapped-operand MFMA.
// (r8 version verbatim — best measured config: 64-row Q blocks, 4 waves)
__global__ __launch_bounds__(256) void attn_mfma(const unsigned short* __restrict__ qkv,
                                                 const unsigned short* __restrict__ vT,
                                                 unsigned short* __restrict__ ctx,
                                                 const int* __restrict__ pnsink,
                                                 const int* __restrict__ pwin) {
    __shared__ unsigned short Ks0[80 * 64];              // rows 64..79: sink K (keys 0..15)
    __shared__ unsigned short Vs0[64 * 64 + 2 * 64 * 8]; // main + V^T sink cols 0..7 / 8..15
    __shared__ unsigned short Ks1[64 * 64];
    __shared__ unsigned short Vs1[64 * 64];
    const int tid = threadIdx.x, lane = tid & 63, w = tid >> 6;
    const int q = lane & 15, g = lane >> 4;
    const int h = blockIdx.y;
    const int bx = ((blockIdx.x & 7) << 3) | (blockIdx.x >> 3);   // XCD-chunked, bijective
    const int i0 = bx << 6;
    const int nsink = *pnsink, wsize = *pwin;
    const int D3 = 2304;
    const int iq = i0 + 16 * w + q;
    const float SC = 0.18033688011112042f;   // 0.125 * log2(e): softmax in exp2 domain

    const int sseg = (lane & 7) ^ (lane >> 3);

    const unsigned short* qrow = qkv + (size_t)iq * D3 + h * 64 + g * 8;
    const bf16x8 aq0 = *(const bf16x8*)(qrow);
    const bf16x8 aq1 = *(const bf16x8*)(qrow + 32);

    float m_run = -1e30f, l_run = 0.f;
    f32x4 octx[4] = {};

    int wlo = i0 - wsize + 1; if (wlo < 0) wlo = 0;
    const int t_lo = (wlo >> 6) << 6;
    const bool ext = (t_lo > 0);             // sinks detached -> fold into tile 0
    const int ntiles = ((i0 - t_lo) >> 6) + 1;

    const int sl01 = q + ((g & 1) << 5);
    const int sl23 = sl01 + 16;
    const int x7 = q & 7;
    const int ck0 = ((0 + g) ^ x7) << 3;
    const int ck1 = ((4 + g) ^ x7) << 3;

#define ASTAGE(KSB, VSB, kb)                                                           \
    {                                                                                  \
        _Pragma("unroll")                                                              \
        for (int i = 0; i < 2; ++i) {                                                  \
            const int ch = w * 2 + i;                                                  \
            const int r = ch * 8 + (lane >> 3);                                        \
            gload16(qkv + (size_t)((kb) + r) * D3 + 768 + h * 64 + sseg * 8,           \
                    (KSB) + ch * 512);                                                 \
            gload16(vT + ((size_t)h * 64 + r) * 4096 + (kb) + sseg * 8,                \
                    (VSB) + ch * 512);                                                 \
        }                                                                              \
    }

    ASTAGE(Ks0, Vs0, t_lo);
    if (ext) {   // one extra gload16 per wave: K rows 0..15 and V^T cols 0..15
        if (w == 0)      gload16(qkv + (size_t)(lane >> 3) * D3 + 768 + h * 64 + sseg * 8, Ks0 + 4096);
        else if (w == 1) gload16(qkv + (size_t)(8 + (lane >> 3)) * D3 + 768 + h * 64 + sseg * 8, Ks0 + 4096 + 512);
        else if (w == 2) gload16(vT + ((size_t)h * 64 + lane) * 4096, Vs0 + 4096);
        else             gload16(vT + ((size_t)h * 64 + lane) * 4096 + 8, Vs0 + 4096 + 1024);
    }

    for (int tt = 0; tt < ntiles; ++tt) {
        __syncthreads();   // buf[tt&1] ready; prev reads of other buf done
        if (tt + 1 < ntiles) {
            const int kbn = t_lo + ((tt + 1) << 6);
            if (tt & 1) ASTAGE(Ks0, Vs0, kbn) else ASTAGE(Ks1, Vs1, kbn);
        }
        const int kb = t_lo + (tt << 6);
        const unsigned short* ks_ = (tt & 1) ? Ks1 : Ks0;
        const unsigned short* vs_ = (tt & 1) ? Vs1 : Vs0;
        const bool extt = ext && (tt == 0);
        const int NB = extt ? 5 : 4;   // wave-uniform

        f32x4 sacc[5] = {};
        __builtin_amdgcn_s_setprio(1);
        #pragma unroll
        for (int nb = 0; nb < 5; ++nb) {
            if (nb < NB) {
                const int rr = (nb * 16 + q) * 64;
                bf16x8 k0 = *(const bf16x8*)(ks_ + rr + ck0);
                bf16x8 k1 = *(const bf16x8*)(ks_ + rr + ck1);
                sacc[nb] = __builtin_amdgcn_mfma_f32_16x16x32_bf16(k0, aq0, sacc[nb], 0, 0, 0);
                sacc[nb] = __builtin_amdgcn_mfma_f32_16x16x32_bf16(k1, aq1, sacc[nb], 0, 0, 0);
            }
        }
        __builtin_amdgcn_s_setprio(0);

        float vmax = -1e30f;
        #pragma unroll
        for (int nb = 0; nb < 5; ++nb)
            if (nb < NB)
                #pragma unroll
                for (int r = 0; r < 4; ++r) {
                    const int slot = nb * 16 + g * 4 + r;
                    const int j = (slot >= 64) ? (slot - 64) : kb + slot;
                    const bool vis = (j <= iq) && ((j < nsink) || (j > iq - wsize));
                    sacc[nb][r] = vis ? sacc[nb][r] * SC : -1e30f;
                    vmax = fmaxf(vmax, sacc[nb][r]);
                }
        vmax = fmaxf(vmax, __shfl_xor(vmax, 16));
        vmax = fmaxf(vmax, __shfl_xor(vmax, 32));

        const bool upd = !__all(vmax <= m_run + 8.f);
        if (upd) {
            const float mn = fmaxf(m_run, vmax);
            const float alpha = __builtin_amdgcn_exp2f(m_run - mn);
            l_run *= alpha;
            #pragma unroll
            for (int nb = 0; nb < 4; ++nb)
                #pragma unroll
                for (int r = 0; r < 4; ++r) octx[nb][r] *= alpha;
            m_run = mn;
        }
        float p[5][4];
        float lsum = 0.f;
        #pragma unroll
        for (int nb = 0; nb < 5; ++nb)
            if (nb < NB)
                #pragma unroll
                for (int r = 0; r < 4; ++r) {
                    const float pv = __builtin_amdgcn_exp2f(sacc[nb][r] - m_run);
                    p[nb][r] = pv;
                    lsum += pv;
                }
        lsum += __shfl_xor(lsum, 16);
        lsum += __shfl_xor(lsum, 32);
        l_run += lsum;

        uint32_t c01[5][2];
        #pragma unroll
        for (int nb = 0; nb < 5; ++nb)
            if (nb < NB) {
                c01[nb][0] = cvt_pk_bf16(p[nb][0], p[nb][1]);
                c01[nb][1] = cvt_pk_bf16(p[nb][2], p[nb][3]);
            }

        __builtin_amdgcn_s_setprio(1);
        #pragma unroll
        for (int ks = 0; ks < 2; ++ks) {
            uint32_t f00 = (uint32_t)__shfl((int)c01[2 * ks + 0][0], sl01);
            uint32_t f01 = (uint32_t)__shfl((int)c01[2 * ks + 1][0], sl01);
            uint32_t f10 = (uint32_t)__shfl((int)c01[2 * ks + 0][1], sl01);
            uint32_t f11 = (uint32_t)__shfl((int)c01[2 * ks + 1][1], sl01);
            uint32_t f20 = (uint32_t)__shfl((int)c01[2 * ks + 0][0], sl23);
            uint32_t f21 = (uint32_t)__shfl((int)c01[2 * ks + 1][0], sl23);
            uint32_t f30 = (uint32_t)__shfl((int)c01[2 * ks + 0][1], sl23);
            uint32_t f31 = (uint32_t)__shfl((int)c01[2 * ks + 1][1], sl23);
            union { uint32_t u[4]; bf16x8 v; } pa;
            pa.u[0] = (g >> 1) ? f01 : f00;
            pa.u[1] = (g >> 1) ? f11 : f10;
            pa.u[2] = (g >> 1) ? f21 : f20;
            pa.u[3] = (g >> 1) ? f31 : f30;
            const int cv = ((ks * 4 + g) ^ x7) << 3;
            #pragma unroll
            for (int nb = 0; nb < 4; ++nb) {
                bf16x8 bv = *(const bf16x8*)(vs_ + (nb * 16 + q) * 64 + cv);
                octx[nb] = __builtin_amdgcn_mfma_f32_16x16x32_bf16(bv, pa.v, octx[nb], 0, 0, 0);
            }
        }
        if (extt) {
            uint32_t e0 = (uint32_t)__shfl((int)c01[4][0], sl01);
            uint32_t e1 = (uint32_t)__shfl((int)c01[4][1], sl01);
            uint32_t e2 = (uint32_t)__shfl((int)c01[4][0], sl23);
            uint32_t e3 = (uint32_t)__shfl((int)c01[4][1], sl23);
            union { uint32_t u[4]; bf16x8 v; } pa;
            const bool lo = (g < 2);
            pa.u[0] = lo ? e0 : 0u;
            pa.u[1] = lo ? e1 : 0u;
            pa.u[2] = lo ? e2 : 0u;
            pa.u[3] = lo ? e3 : 0u;
            const unsigned short* vb = vs_ + 4096 + ((g & 1) << 10);
            #pragma unroll
            for (int nb = 0; nb < 4; ++nb) {
                bf16x8 bv = *(const bf16x8*)(vb + (nb * 16 + q) * 8);
                octx[nb] = __builtin_amdgcn_mfma_f32_16x16x32_bf16(bv, pa.v, octx[nb], 0, 0, 0);
            }
        }
        __builtin_amdgcn_s_setprio(0);
    }
#undef ASTAGE

    const float inv = (l_run > 0.f) ? 1.f / l_run : 0.f;
    unsigned short* crow = ctx + (size_t)iq * 768 + h * 64 + g * 4;
    #pragma unroll
    for (int nb = 0; nb < 4; ++nb) {
        uint2 st;
        st.x = cvt_pk_bf16(octx[nb][0] * inv, octx[nb][1] * inv);
        st.y = cvt_pk_bf16(octx[nb][2] * inv, octx[nb][3] * inv);
        *(uint2*)(crow + nb * 16) = st;
    }
}

extern "C" void kernel_launch(void* const* d_in, const int* in_sizes, int n_in,
                              void* d_out, int out_size, void* d_ws, size_t ws_size,
                              hipStream_t stream) {
    const float* x      = (const float*)d_in[0];
    const float* w_attn = (const float*)d_in[1];
    const float* b_attn = (const float*)d_in[2];
    const float* w_proj = (const float*)d_in[3];
    const float* b_proj = (const float*)d_in[4];
    const int*   pnsink = (const int*)d_in[5];
    const int*   pwin   = (const int*)d_in[6];
    float* out = (float*)d_out;

    const int D = 768, S = 4096, N1 = 3 * D;

    unsigned short* xbf   = (unsigned short*)d_ws;
    unsigned short* waT   = xbf + (size_t)S * D;
    unsigned short* wpT   = waT + (size_t)N1 * D;
    unsigned short* qkvbf = wpT + (size_t)D * D;
    unsigned short* ctxbf = qkvbf + (size_t)S * N1;
    unsigned short* vTbf  = ctxbf + (size_t)S * D;

    // merged prep: cast x + transpose both weights (one launch)
    prep<<<2112, 256, 0, stream>>>(x, w_attn, w_proj, xbf, waT, wpT);

    // GEMM1 (2-phase 64x128 tiles, 1152 blocks ~3/CU): qkv; V third -> vT
    {
        dim3 g(N1 / 128, S / 64);
        gemm_bf16<1, 1><<<g, 256, 0, stream>>>(xbf, waT, b_attn, qkvbf, vTbf, S, N1, D);
    }
    // attention -> ctx bf16 [S, D]  (r8 proven config)
    {
        dim3 g(S / 64, 12);
        attn_mfma<<<g, 256, 0, stream>>>(qkvbf, vTbf, ctxbf, pnsink, pwin);
    }
    // GEMM2 (64x128 tiles, 384 blocks): out = ctx @ w_proj + b_proj -> f32
    {
        dim3 g(D / 128, S / 64);
        gemm_bf16<0, 0><<<g, 256, 0, stream>>>(ctxbf, wpT, b_proj, out, nullptr, S, D, D);
    }
}